// Round 24
// baseline (244.051 us; speedup 1.0000x reference)
//
#include <hip/hip_runtime.h>
#include <hip/hip_bf16.h>

// ResnetBlockDDPMpp_Adagn: B=8, CIN=COUT=256, H=W=64, G=32, K=3
// Round 24 (on R23 regression 243.6us -> revert to R22 structure, 236.2us):
//  - R23 lesson: separate h2 (+32MB round-trip) cost MORE than conv1's 3x
//    adagn recompute in halo staging (rides under MFMA/latency). Fused wins.
//  - Keep from R23: prep float4 dots (strictly less serial work).
//  - Everything else = R22 exactly (best measured: 236.2us).

#define EPSV 1e-6f

typedef short    s16x8 __attribute__((ext_vector_type(8)));   // raw 8x16b storage
typedef _Float16 h16x8 __attribute__((ext_vector_type(8)));   // fp16 math/MFMA
typedef float    f32x4 __attribute__((ext_vector_type(4)));

__device__ __forceinline__ float silu_f(float v){ return v / (1.f + __expf(-v)); }
__device__ __forceinline__ unsigned short f2h(float f){
  _Float16 h = (_Float16)f; unsigned short u; __builtin_memcpy(&u, &h, 2); return u;
}
__device__ __forceinline__ float h2f(unsigned short u){
  _Float16 h; __builtin_memcpy(&h, &u, 2); return (float)h;
}

// ---------------- ws layout (float units) ----------------
#define WS_H0B     0            // 8*4096*256 fp16
#define WS_H1B     4194304      // 8*4096*256 fp16
#define WS_OFFT    8388608      // 8*4096*27 fp32
#define WS_WTD     9273344      // dcn fp16 [9][32][256][8]
#define WS_WTC     9568256      // conv1 fp16 same
#define WS_OFFWTB  9863168      // offw fp16 [9][32][32][8]
#define WS_STYLE0  9900032
#define WS_STYLE1  9904128
#define WS_TPROJ   9908224
#define WS_MU0     9910272
#define WS_RS0     9910528
#define WS_MU1     9910784
#define WS_RS1     9911040
// end 9,911,296 floats = 39.6 MB

#define SSTR 272   // LDS row stride (ushorts): 544B, 16B-aligned

// ---------- prep: weight packs + tiny GEMMs (float4 dots) ----------
__global__ __launch_bounds__(256) void prep_kernel(
    const float* __restrict__ zemb, const float* __restrict__ temb,
    const float* __restrict__ g0w, const float* __restrict__ g0b,
    const float* __restrict__ g1w, const float* __restrict__ g1b,
    const float* __restrict__ d0w, const float* __restrict__ d0b,
    const float* __restrict__ dcn_w, const float* __restrict__ c1w,
    const float* __restrict__ offw,
    unsigned short* __restrict__ wtd, unsigned short* __restrict__ wtc,
    unsigned short* __restrict__ offwtb,
    float* __restrict__ style0, float* __restrict__ style1, float* __restrict__ tproj)
{
  int blk = blockIdx.x, t = threadIdx.x;
  if (blk < 2304) {                       // dcn pack: e=((k*32+c8)*256+o)*8+j
    int e = blk*256 + t;
    int j = e & 7, o = (e >> 3) & 255, c8 = (e >> 11) & 31, k = e >> 16;
    wtd[e] = f2h(dcn_w[((o*256 + c8*8 + j)*9) + k]);
  } else if (blk < 4608) {                // conv1 pack
    int e = (blk-2304)*256 + t;
    int j = e & 7, o = (e >> 3) & 255, c8 = (e >> 11) & 31, k = e >> 16;
    wtc[e] = f2h(c1w[((o*256 + c8*8 + j)*9) + k]);
  } else if (blk < 4896) {                // offw pack: [9][32 c8][32 o][8 j], oc>=27 -> 0
    int e = (blk-4608)*256 + t;           // 73728 elems
    int j = e & 7, o = (e >> 3) & 31, c8 = (e >> 8) & 31, k = e >> 13;
    int c = c8*8 + j;
    offwtb[e] = (o < 27) ? f2h(offw[((o*256 + c)*9) + k]) : (unsigned short)0;
  } else if (blk < 4912) {                // style0 = zemb @ g0w.T + g0b (8x512)
    int e = (blk-4896)*256 + t; int b = e >> 9, j = e & 511;
    float s = g0b[j];
    const f32x4* z = (const f32x4*)(zemb + b*256);
    const f32x4* w = (const f32x4*)(g0w + j*256);
    for (int i = 0; i < 64; ++i) {
      f32x4 zv = z[i], wv = w[i];
      s += zv.x*wv.x + zv.y*wv.y + zv.z*wv.z + zv.w*wv.w;
    }
    style0[e] = s;
  } else if (blk < 4928) {                // style1
    int e = (blk-4912)*256 + t; int b = e >> 9, j = e & 511;
    float s = g1b[j];
    const f32x4* z = (const f32x4*)(zemb + b*256);
    const f32x4* w = (const f32x4*)(g1w + j*256);
    for (int i = 0; i < 64; ++i) {
      f32x4 zv = z[i], wv = w[i];
      s += zv.x*wv.x + zv.y*wv.y + zv.z*wv.z + zv.w*wv.w;
    }
    style1[e] = s;
  } else {                                // tproj = silu(temb) @ d0w.T + d0b (8x256)
    int e = (blk-4928)*256 + t; int b = e >> 8, o = e & 255;
    float s = d0b[o];
    const f32x4* tb = (const f32x4*)(temb + b*512);
    const f32x4* w  = (const f32x4*)(d0w + o*512);
    for (int i = 0; i < 128; ++i) {
      f32x4 tv = tb[i], wv = w[i];
      s += silu_f(tv.x)*wv.x + silu_f(tv.y)*wv.y + silu_f(tv.z)*wv.z + silu_f(tv.w)*wv.w;
    }
    tproj[e] = s;
  }
}

// ---------- reductions ----------
__device__ __forceinline__ void block_reduce2(float& s, float& q){
  for (int off = 32; off > 0; off >>= 1) {
    s += __shfl_down(s, off, 64);
    q += __shfl_down(q, off, 64);
  }
  __shared__ float ss[4], qs[4];
  int wid = threadIdx.x >> 6, lane = threadIdx.x & 63;
  if (lane == 0) { ss[wid] = s; qs[wid] = q; }
  __syncthreads();
  if (threadIdx.x == 0) { s = ss[0]+ss[1]+ss[2]+ss[3]; q = qs[0]+qs[1]+qs[2]+qs[3]; }
}

__global__ __launch_bounds__(256) void gn0_stats_kernel(
    const float* __restrict__ x, float* __restrict__ mu, float* __restrict__ rs)
{
  int blk = blockIdx.x;  // b*32+g ; NCHW group = 32768 contiguous
  const float4* p4 = (const float4*)(x + (size_t)blk*32768);
  float s = 0.f, q = 0.f;
  for (int i = threadIdx.x; i < 8192; i += 256) {
    float4 v = p4[i];
    s += v.x+v.y+v.z+v.w;
    q += v.x*v.x + v.y*v.y + v.z*v.z + v.w*v.w;
  }
  block_reduce2(s, q);
  if (threadIdx.x == 0) {
    float m = s * (1.f/32768.f);
    float var = q * (1.f/32768.f) - m*m;
    mu[blk] = m; rs[blk] = rsqrtf(var + EPSV);
  }
}

// GN stats over h1 (fp16 NHWC)
__global__ __launch_bounds__(256) void gn1_stats_kernel(
    const unsigned short* __restrict__ h1h, float* __restrict__ mu, float* __restrict__ rs)
{
  int blk = blockIdx.x;  // b*32+g
  int b = blk >> 5, g = blk & 31;
  const unsigned short* base = h1h + (size_t)b*1048576 + g*8;
  float s = 0.f, q = 0.f;
  for (int px = threadIdx.x; px < 4096; px += 256) {
    s16x8 v = *(const s16x8*)(base + (size_t)px*256);
    #pragma unroll
    for (int e = 0; e < 8; ++e) {
      float f = h2f((unsigned short)v[e]);
      s += f; q += f*f;
    }
  }
  block_reduce2(s, q);
  if (threadIdx.x == 0) {
    float m = s * (1.f/32768.f);
    float var = q * (1.f/32768.f) - m*m;
    mu[blk] = m; rs[blk] = rsqrtf(var + EPSV);
  }
}

// ---------- h0 = silu(adagn(x)) NCHW -> NHWC fp16 ----------
__global__ __launch_bounds__(256) void h0_kernel(
    const float* __restrict__ x, const float* __restrict__ style0,
    const float* __restrict__ mu, const float* __restrict__ rs,
    unsigned short* __restrict__ h0h)
{
  int blk = blockIdx.x;          // b(8) x ptile(64) x ctile(8)
  int b  = blk >> 9;
  int pt = (blk >> 3) & 63;
  int ct = blk & 7;
  __shared__ float tile[32][65];
  int p0 = pt*64, c0 = ct*32;
  int t = threadIdx.x;
  for (int it = 0; it < 8; ++it) {
    int c = c0 + it*4 + (t >> 6);
    int p = p0 + (t & 63);
    float v = x[((size_t)(b*256 + c))*4096 + p];
    int g = c >> 3;
    float m  = mu[b*32+g], r = rs[b*32+g];
    float ga = style0[b*512 + c], be = style0[b*512 + 256 + c];
    float u = ga * (v - m) * r + be;
    tile[c - c0][p - p0] = silu_f(u);
  }
  __syncthreads();
  for (int it = 0; it < 8; ++it) {
    int pp = it*8 + (t >> 5);
    int cc = t & 31;
    h0h[((size_t)(b*4096 + p0 + pp))*256 + c0 + cc] = f2h(tile[cc][pp]);
  }
}

// ---------- offset conv MFMA (fp16): 32 px x 32 oc (27 used) ----------
__global__ __launch_bounds__(256) void offset_mfma_kernel(
    const unsigned short* __restrict__ h0h, const unsigned short* __restrict__ wt,
    const float* __restrict__ off_b, float* __restrict__ off_t)
{
  int bid = blockIdx.x;
  int b  = bid & 7;                            // XCD swizzle
  int p0 = (bid >> 3) * 32;
  int y = p0 >> 6, xb = p0 & 63;
  int t = threadIdx.x;
  int lane = t & 63, wv = t >> 6;
  int r = lane & 15, g = lane >> 4;

  __shared__ unsigned short aw[3*34*SSTR];

  const unsigned short* hbase = h0h + (size_t)b*1048576;
  for (int idx = t; idx < 3264; idx += 256) {
    int row = idx / 1088, rem = idx - row*1088;
    int px = rem >> 5, c8 = rem & 31;
    int yy = y + row - 1, xx = xb - 1 + px;
    s16x8 v = {0,0,0,0,0,0,0,0};
    if (yy >= 0 && yy < 64 && xx >= 0 && xx < 64)
      v = *(const s16x8*)&hbase[((size_t)yy*64 + xx)*256 + c8*8];
    *(s16x8*)&aw[(row*34 + px)*SSTR + c8*8] = v;
  }
  __syncthreads();

  int m = wv & 1, n = wv >> 1;                 // wave -> (px half, oc half)
  f32x4 acc = {0.f,0.f,0.f,0.f};
  for (int k = 0; k < 9; ++k) {
    int ky = k/3, kxo = k%3;
    const unsigned short* abase = &aw[(ky*34)*SSTR];
    const unsigned short* wk = wt + (size_t)k*8192;   // [32 c8][32 o][8]
    #pragma unroll
    for (int kc = 0; kc < 8; ++kc) {
      h16x8 a  = *(const h16x8*)&abase[(kxo + m*16 + r)*SSTR + kc*32 + g*8];
      h16x8 bf = *(const h16x8*)&wk[(size_t)((kc*4 + g)*32 + n*16 + r)*8];
      acc = __builtin_amdgcn_mfma_f32_16x16x32_f16(a, bf, acc, 0, 0, 0);
    }
  }

  int oc = n*16 + r;
  if (oc < 27) {
    float bs = off_b[oc];
    #pragma unroll
    for (int j = 0; j < 4; ++j) {
      int px = m*16 + g*4 + j;
      off_t[((size_t)(b*4096) + p0 + px)*27 + oc] = acc[j] + bs;
    }
  }
}

// ---------- deformable conv (fp16): M=32, 4 blocks/CU, pre[8] resident ----------
__global__ __launch_bounds__(512, 2) void deform_mfma_kernel(
    const unsigned short* __restrict__ h0h, const float* __restrict__ off_t,
    const unsigned short* __restrict__ wt, const float* __restrict__ dcn_b,
    const float* __restrict__ tproj, unsigned short* __restrict__ h1h)
{
  int bid = blockIdx.x;                        // 1024 blocks
  int b  = bid & 7;                            // XCD swizzle (1024 % 8 == 0)
  int p0 = (bid >> 3) * 32;                    // 32 px, same row
  int t = threadIdx.x;                         // 0..511
  int lane = t & 63, wv = t >> 6;              // 8 waves
  int r = lane & 15, g = lane >> 4;

  __shared__ unsigned short samp[2][32*SSTR];  // dbuf 34.8KB
  __shared__ int    pki[288];
  __shared__ float4 pkw[288];                  // total 40.6KB -> 4 blk/CU

  for (int tp = t; tp < 288; tp += 512) {      // 32 px x 9 taps
    int i = tp / 9, k = tp - i*9;
    int p = p0 + i; int y = p >> 6, xq = p & 63;
    const float* ob = off_t + ((size_t)(b*4096) + p)*27;
    float dy = ob[2*k], dx = ob[2*k+1];
    float mask = 1.f / (1.f + __expf(-ob[18+k]));
    float py = dy + (float)(k/3 + y - 1);
    float px = dx + (float)(k%3 + xq - 1);
    float fy0 = floorf(py), fx0 = floorf(px);
    float wy1 = py - fy0, wx1 = px - fx0;
    int y0 = (int)fy0, x0 = (int)fx0, y1 = y0+1, x1 = x0+1;
    float vy0 = (y0 >= 0 && y0 < 64) ? 1.f : 0.f;
    float vy1 = (y1 >= 0 && y1 < 64) ? 1.f : 0.f;
    float vx0 = (x0 >= 0 && x0 < 64) ? 1.f : 0.f;
    float vx1 = (x1 >= 0 && x1 < 64) ? 1.f : 0.f;
    int iy0 = min(max(y0,0),63), ix0 = min(max(x0,0),63);
    int iy1 = min(max(y1,0),63), ix1 = min(max(x1,0),63);
    pki[tp] = iy0 | (ix0 << 8) | (iy1 << 16) | (ix1 << 24);
    float4 w;
    w.x = (1.f-wy1)*(1.f-wx1)*vy0*vx0*mask;
    w.y = (1.f-wy1)*wx1      *vy0*vx1*mask;
    w.z = wy1      *(1.f-wx1)*vy1*vx0*mask;
    w.w = wy1      *wx1      *vy1*vx1*mask;
    pkw[tp] = w;
  }
  __syncthreads();

  f32x4 zero4 = {0.f,0.f,0.f,0.f};
  f32x4 acc[2][2];
  #pragma unroll
  for (int m = 0; m < 2; ++m) { acc[m][0] = zero4; acc[m][1] = zero4; }

  const unsigned short* hb = h0h + (size_t)b*1048576;
  int px = t >> 4;                             // 16 threads per pixel (32 px)
  int ci = (t & 15) * 16;                      // 16 contiguous channels each
  int o_base = wv*32 + r;                      // 8 waves x UNIQUE 32-out slice

  h16x8 pre[8];                                // 4 corners x 16ch = 32 VGPR
  auto loadk = [&](int kk) {
    int tp = px*9 + kk;
    int pk = pki[tp];
    int iy0 = pk & 255, ix0 = (pk >> 8) & 255, iy1 = (pk >> 16) & 255, ix1 = (pk >> 24) & 255;
    const h16x8* q00 = (const h16x8*)(hb + ((size_t)iy0*64 + ix0)*256 + ci);
    const h16x8* q01 = (const h16x8*)(hb + ((size_t)iy0*64 + ix1)*256 + ci);
    const h16x8* q10 = (const h16x8*)(hb + ((size_t)iy1*64 + ix0)*256 + ci);
    const h16x8* q11 = (const h16x8*)(hb + ((size_t)iy1*64 + ix1)*256 + ci);
    pre[0] = q00[0]; pre[1] = q00[1];
    pre[2] = q01[0]; pre[3] = q01[1];
    pre[4] = q10[0]; pre[5] = q10[1];
    pre[6] = q11[0]; pre[7] = q11[1];
  };

  loadk(0);
  for (int k = 0; k < 9; ++k) {
    { // pk-fma weighted sum from prefetch regs -> LDS buf k&1
      int tp = px*9 + k;
      float4 w = pkw[tp];
      _Float16 w00 = (_Float16)w.x, w01 = (_Float16)w.y;
      _Float16 w10 = (_Float16)w.z, w11 = (_Float16)w.w;
      unsigned short* sp = &samp[k & 1][px*SSTR + ci];
      #pragma unroll
      for (int ch = 0; ch < 2; ++ch) {
        h16x8 o = pre[ch]*w00 + pre[2+ch]*w01 + pre[4+ch]*w10 + pre[6+ch]*w11;
        *(h16x8*)(sp + ch*8) = o;
      }
    }
    if (k < 8) loadk(k+1);                     // pre[8] stays resident
    asm volatile("s_waitcnt lgkmcnt(0)" ::: "memory");
    __builtin_amdgcn_s_barrier();

    const unsigned short* sb = samp[k & 1];
    const unsigned short* wk = wt + (size_t)k*65536;   // [32][256][8] this tap
    #pragma unroll
    for (int kc = 0; kc < 8; ++kc) {
      h16x8 a0 = *(const h16x8*)&sb[(     r)*SSTR + kc*32 + g*8];
      h16x8 a1 = *(const h16x8*)&sb[(16 + r)*SSTR + kc*32 + g*8];
      const unsigned short* wb = wk + (size_t)(kc*4 + g)*2048 + o_base*8;
      h16x8 b0 = *(const h16x8*)&wb[  0*8];
      h16x8 b1 = *(const h16x8*)&wb[ 16*8];
      acc[0][0] = __builtin_amdgcn_mfma_f32_16x16x32_f16(a0, b0, acc[0][0], 0, 0, 0);
      acc[0][1] = __builtin_amdgcn_mfma_f32_16x16x32_f16(a0, b1, acc[0][1], 0, 0, 0);
      acc[1][0] = __builtin_amdgcn_mfma_f32_16x16x32_f16(a1, b0, acc[1][0], 0, 0, 0);
      acc[1][1] = __builtin_amdgcn_mfma_f32_16x16x32_f16(a1, b1, acc[1][1], 0, 0, 0);
    }
    // no second barrier: next tap writes the other buffer (WAR safe)
  }

  #pragma unroll
  for (int nn = 0; nn < 2; ++nn) {
    int o = o_base + nn*16;
    float bs = dcn_b[o] + tproj[b*256 + o];
    #pragma unroll
    for (int m = 0; m < 2; ++m)
      #pragma unroll
      for (int j = 0; j < 4; ++j) {
        int pxl = m*16 + g*4 + j;
        h1h[((size_t)(b*4096) + p0 + pxl)*256 + o] = f2h(acc[m][nn][j] + bs);
      }
  }
}

// ---------- conv1 (fp16) M=32, adagn/silu fused staging, 2 blocks/CU ----------
__global__ __launch_bounds__(512, 2) void conv1_mfma_kernel(
    const unsigned short* __restrict__ h1h, const float* __restrict__ style1,
    const float* __restrict__ mu, const float* __restrict__ rs,
    const unsigned short* __restrict__ wt,
    const float* __restrict__ c1_b, const float* __restrict__ x,
    float* __restrict__ out)
{
  int bid = blockIdx.x;                        // 1024 blocks
  int b  = bid & 7;                            // XCD swizzle
  int p0 = (bid >> 3) * 32;
  int y = p0 >> 6, xb = p0 & 63;
  int t = threadIdx.x;                         // 0..511
  int lane = t & 63, wv = t >> 6;              // 8 waves
  int r = lane & 15, g = lane >> 4;

  __shared__ unsigned short aw[3*34*SSTR];     // 55.5KB -> 2 blk/CU

  const unsigned short* h1base = h1h + (size_t)b*1048576;
  for (int idx = t; idx < 3264; idx += 512) {  // 3 rows * 34 px * 32 chunks(8c)
    int row = idx / 1088, rem = idx - row*1088;
    int px = rem >> 5, c8 = rem & 31;
    int yy = y + row - 1, xx = xb - 1 + px;
    s16x8 v = {0,0,0,0,0,0,0,0};
    if (yy >= 0 && yy < 64 && xx >= 0 && xx < 64) {
      s16x8 h = *(const s16x8*)&h1base[((size_t)yy*64 + xx)*256 + c8*8];
      float m  = mu[b*32+c8], rr = rs[b*32+c8];
      #pragma unroll
      for (int j = 0; j < 8; ++j) {
        int c = c8*8 + j;
        float ga = style1[b*512 + c], be = style1[b*512 + 256 + c];
        float u = ga * (h2f((unsigned short)h[j]) - m) * rr + be;
        v[j] = (short)f2h(silu_f(u));
      }
    }
    *(s16x8*)&aw[(row*34 + px)*SSTR + c8*8] = v;
  }
  __syncthreads();

  f32x4 zero4 = {0.f,0.f,0.f,0.f};
  f32x4 acc[2][2];
  #pragma unroll
  for (int m = 0; m < 2; ++m) { acc[m][0] = zero4; acc[m][1] = zero4; }

  int o_base = wv*32 + r;                      // 8 waves x UNIQUE 32-out slice
  for (int k = 0; k < 9; ++k) {
    int ky = k/3, kxo = k%3;
    const unsigned short* abase = &aw[(ky*34)*SSTR];
    const unsigned short* wk = wt + (size_t)k*65536;
    #pragma unroll
    for (int kc = 0; kc < 8; ++kc) {
      h16x8 a0 = *(const h16x8*)&abase[(kxo +      r)*SSTR + kc*32 + g*8];
      h16x8 a1 = *(const h16x8*)&abase[(kxo + 16 + r)*SSTR + kc*32 + g*8];
      const unsigned short* wb = wk + (size_t)(kc*4 + g)*2048 + o_base*8;
      h16x8 b0 = *(const h16x8*)&wb[  0*8];
      h16x8 b1 = *(const h16x8*)&wb[ 16*8];
      acc[0][0] = __builtin_amdgcn_mfma_f32_16x16x32_f16(a0, b0, acc[0][0], 0, 0, 0);
      acc[0][1] = __builtin_amdgcn_mfma_f32_16x16x32_f16(a0, b1, acc[0][1], 0, 0, 0);
      acc[1][0] = __builtin_amdgcn_mfma_f32_16x16x32_f16(a1, b0, acc[1][0], 0, 0, 0);
      acc[1][1] = __builtin_amdgcn_mfma_f32_16x16x32_f16(a1, b1, acc[1][1], 0, 0, 0);
    }
  }

  #pragma unroll
  for (int nn = 0; nn < 2; ++nn) {
    int o = o_base + nn*16;
    float cb = c1_b[o];
    #pragma unroll
    for (int m = 0; m < 2; ++m)
      #pragma unroll
      for (int j = 0; j < 4; ++j) {
        int pxl = m*16 + g*4 + j;
        size_t oi = ((size_t)(b*256 + o))*4096 + p0 + pxl;
        out[oi] = x[oi] + acc[m][nn][j] + cb;
      }
  }
}

extern "C" void kernel_launch(void* const* d_in, const int* in_sizes, int n_in,
                              void* d_out, int out_size, void* d_ws, size_t ws_size,
                              hipStream_t stream) {
  const float* x    = (const float*)d_in[0];
  const float* temb = (const float*)d_in[1];
  const float* zemb = (const float*)d_in[2];
  const float* g0w  = (const float*)d_in[3];
  const float* g0b  = (const float*)d_in[4];
  const float* offw = (const float*)d_in[5];
  const float* offb = (const float*)d_in[6];
  const float* dcnw = (const float*)d_in[7];
  const float* dcnb = (const float*)d_in[8];
  const float* d0w  = (const float*)d_in[9];
  const float* d0b  = (const float*)d_in[10];
  const float* g1w  = (const float*)d_in[11];
  const float* g1b  = (const float*)d_in[12];
  const float* c1w  = (const float*)d_in[13];
  const float* c1b  = (const float*)d_in[14];
  float* out = (float*)d_out;
  float* ws  = (float*)d_ws;

  unsigned short* h0h = (unsigned short*)(ws + WS_H0B);
  unsigned short* h1h = (unsigned short*)(ws + WS_H1B);
  float* off_t   = ws + WS_OFFT;
  unsigned short* wtd  = (unsigned short*)(ws + WS_WTD);
  unsigned short* wtc  = (unsigned short*)(ws + WS_WTC);
  unsigned short* owtb = (unsigned short*)(ws + WS_OFFWTB);
  float* style0  = ws + WS_STYLE0;
  float* style1  = ws + WS_STYLE1;
  float* tproj   = ws + WS_TPROJ;
  float* mu0     = ws + WS_MU0;
  float* rs0     = ws + WS_RS0;
  float* mu1     = ws + WS_MU1;
  float* rs1     = ws + WS_RS1;

  prep_kernel<<<4936, 256, 0, stream>>>(zemb, temb, g0w, g0b, g1w, g1b, d0w, d0b,
                                        dcnw, c1w, offw, wtd, wtc, owtb,
                                        style0, style1, tproj);
  gn0_stats_kernel<<<256, 256, 0, stream>>>(x, mu0, rs0);
  h0_kernel<<<4096, 256, 0, stream>>>(x, style0, mu0, rs0, h0h);
  offset_mfma_kernel<<<1024, 256, 0, stream>>>(h0h, owtb, offb, off_t);
  deform_mfma_kernel<<<1024, 512, 0, stream>>>(h0h, off_t, wtd, dcnb, tproj, h1h);
  gn1_stats_kernel<<<256, 256, 0, stream>>>(h1h, mu1, rs1);
  conv1_mfma_kernel<<<1024, 512, 0, stream>>>(h1h, style1, mu1, rs1, wtc, c1b, x, out);
}

// Round 25
// 236.404 us; speedup vs baseline: 1.0323x; 1.0323x over previous
//
#include <hip/hip_runtime.h>
#include <hip/hip_bf16.h>

// ResnetBlockDDPMpp_Adagn: B=8, CIN=COUT=256, H=W=64, G=32, K=3
// Round 25: exact revert to R22 (best measured 236.2us).
//  - R23/R24 showed prep float4 "optimization" cost ~8us (two measurements
//    at ~244 vs R22's 236.2; deform/conv1 counters identical) - likely reg
//    pressure across prep's shared-allocation branches. Reverted.
//  - Validated stack: fp16 MFMA path (R18), aligned stride-272 LDS (R19),
//    M=32 tiles / 4 blk-CU deform / pre[8] resident (R22), fused conv1
//    adagn staging (R23 ablation), XCD swizzle (R7).

#define EPSV 1e-6f

typedef short    s16x8 __attribute__((ext_vector_type(8)));   // raw 8x16b storage
typedef _Float16 h16x8 __attribute__((ext_vector_type(8)));   // fp16 math/MFMA
typedef float    f32x4 __attribute__((ext_vector_type(4)));

__device__ __forceinline__ float silu_f(float v){ return v / (1.f + __expf(-v)); }
__device__ __forceinline__ unsigned short f2h(float f){
  _Float16 h = (_Float16)f; unsigned short u; __builtin_memcpy(&u, &h, 2); return u;
}
__device__ __forceinline__ float h2f(unsigned short u){
  _Float16 h; __builtin_memcpy(&h, &u, 2); return (float)h;
}

// ---------------- ws layout (float units) ----------------
#define WS_H0B     0            // 8*4096*256 fp16
#define WS_H1B     4194304      // 8*4096*256 fp16
#define WS_OFFT    8388608      // 8*4096*27 fp32
#define WS_WTD     9273344      // dcn fp16 [9][32][256][8]
#define WS_WTC     9568256      // conv1 fp16 same
#define WS_OFFWTB  9863168      // offw fp16 [9][32][32][8]
#define WS_STYLE0  9900032
#define WS_STYLE1  9904128
#define WS_TPROJ   9908224
#define WS_MU0     9910272
#define WS_RS0     9910528
#define WS_MU1     9910784
#define WS_RS1     9911040
// end 9,911,296 floats = 39.6 MB

#define SSTR 272   // LDS row stride (ushorts): 544B, 16B-aligned

// ---------- prep: weight packs + tiny GEMMs ----------
__global__ __launch_bounds__(256) void prep_kernel(
    const float* __restrict__ zemb, const float* __restrict__ temb,
    const float* __restrict__ g0w, const float* __restrict__ g0b,
    const float* __restrict__ g1w, const float* __restrict__ g1b,
    const float* __restrict__ d0w, const float* __restrict__ d0b,
    const float* __restrict__ dcn_w, const float* __restrict__ c1w,
    const float* __restrict__ offw,
    unsigned short* __restrict__ wtd, unsigned short* __restrict__ wtc,
    unsigned short* __restrict__ offwtb,
    float* __restrict__ style0, float* __restrict__ style1, float* __restrict__ tproj)
{
  int blk = blockIdx.x, t = threadIdx.x;
  if (blk < 2304) {                       // dcn pack: e=((k*32+c8)*256+o)*8+j
    int e = blk*256 + t;
    int j = e & 7, o = (e >> 3) & 255, c8 = (e >> 11) & 31, k = e >> 16;
    wtd[e] = f2h(dcn_w[((o*256 + c8*8 + j)*9) + k]);
  } else if (blk < 4608) {                // conv1 pack
    int e = (blk-2304)*256 + t;
    int j = e & 7, o = (e >> 3) & 255, c8 = (e >> 11) & 31, k = e >> 16;
    wtc[e] = f2h(c1w[((o*256 + c8*8 + j)*9) + k]);
  } else if (blk < 4896) {                // offw pack: [9][32 c8][32 o][8 j], oc>=27 -> 0
    int e = (blk-4608)*256 + t;           // 73728 elems
    int j = e & 7, o = (e >> 3) & 31, c8 = (e >> 8) & 31, k = e >> 13;
    int c = c8*8 + j;
    offwtb[e] = (o < 27) ? f2h(offw[((o*256 + c)*9) + k]) : (unsigned short)0;
  } else if (blk < 4912) {                // style0 = zemb @ g0w.T + g0b (8x512)
    int e = (blk-4896)*256 + t; int b = e >> 9, j = e & 511;
    float s = g0b[j];
    const float* z = zemb + b*256; const float* w = g0w + j*256;
    for (int i = 0; i < 256; ++i) s += z[i]*w[i];
    style0[e] = s;
  } else if (blk < 4928) {                // style1
    int e = (blk-4912)*256 + t; int b = e >> 9, j = e & 511;
    float s = g1b[j];
    const float* z = zemb + b*256; const float* w = g1w + j*256;
    for (int i = 0; i < 256; ++i) s += z[i]*w[i];
    style1[e] = s;
  } else {                                // tproj = silu(temb) @ d0w.T + d0b (8x256)
    int e = (blk-4928)*256 + t; int b = e >> 8, o = e & 255;
    float s = d0b[o];
    const float* tb = temb + b*512; const float* w = d0w + o*512;
    for (int i = 0; i < 512; ++i) s += silu_f(tb[i])*w[i];
    tproj[e] = s;
  }
}

// ---------- reductions ----------
__device__ __forceinline__ void block_reduce2(float& s, float& q){
  for (int off = 32; off > 0; off >>= 1) {
    s += __shfl_down(s, off, 64);
    q += __shfl_down(q, off, 64);
  }
  __shared__ float ss[4], qs[4];
  int wid = threadIdx.x >> 6, lane = threadIdx.x & 63;
  if (lane == 0) { ss[wid] = s; qs[wid] = q; }
  __syncthreads();
  if (threadIdx.x == 0) { s = ss[0]+ss[1]+ss[2]+ss[3]; q = qs[0]+qs[1]+qs[2]+qs[3]; }
}

__global__ __launch_bounds__(256) void gn0_stats_kernel(
    const float* __restrict__ x, float* __restrict__ mu, float* __restrict__ rs)
{
  int blk = blockIdx.x;  // b*32+g ; NCHW group = 32768 contiguous
  const float4* p4 = (const float4*)(x + (size_t)blk*32768);
  float s = 0.f, q = 0.f;
  for (int i = threadIdx.x; i < 8192; i += 256) {
    float4 v = p4[i];
    s += v.x+v.y+v.z+v.w;
    q += v.x*v.x + v.y*v.y + v.z*v.z + v.w*v.w;
  }
  block_reduce2(s, q);
  if (threadIdx.x == 0) {
    float m = s * (1.f/32768.f);
    float var = q * (1.f/32768.f) - m*m;
    mu[blk] = m; rs[blk] = rsqrtf(var + EPSV);
  }
}

// GN stats over h1 (fp16 NHWC)
__global__ __launch_bounds__(256) void gn1_stats_kernel(
    const unsigned short* __restrict__ h1h, float* __restrict__ mu, float* __restrict__ rs)
{
  int blk = blockIdx.x;  // b*32+g
  int b = blk >> 5, g = blk & 31;
  const unsigned short* base = h1h + (size_t)b*1048576 + g*8;
  float s = 0.f, q = 0.f;
  for (int px = threadIdx.x; px < 4096; px += 256) {
    s16x8 v = *(const s16x8*)(base + (size_t)px*256);
    #pragma unroll
    for (int e = 0; e < 8; ++e) {
      float f = h2f((unsigned short)v[e]);
      s += f; q += f*f;
    }
  }
  block_reduce2(s, q);
  if (threadIdx.x == 0) {
    float m = s * (1.f/32768.f);
    float var = q * (1.f/32768.f) - m*m;
    mu[blk] = m; rs[blk] = rsqrtf(var + EPSV);
  }
}

// ---------- h0 = silu(adagn(x)) NCHW -> NHWC fp16 ----------
__global__ __launch_bounds__(256) void h0_kernel(
    const float* __restrict__ x, const float* __restrict__ style0,
    const float* __restrict__ mu, const float* __restrict__ rs,
    unsigned short* __restrict__ h0h)
{
  int blk = blockIdx.x;          // b(8) x ptile(64) x ctile(8)
  int b  = blk >> 9;
  int pt = (blk >> 3) & 63;
  int ct = blk & 7;
  __shared__ float tile[32][65];
  int p0 = pt*64, c0 = ct*32;
  int t = threadIdx.x;
  for (int it = 0; it < 8; ++it) {
    int c = c0 + it*4 + (t >> 6);
    int p = p0 + (t & 63);
    float v = x[((size_t)(b*256 + c))*4096 + p];
    int g = c >> 3;
    float m  = mu[b*32+g], r = rs[b*32+g];
    float ga = style0[b*512 + c], be = style0[b*512 + 256 + c];
    float u = ga * (v - m) * r + be;
    tile[c - c0][p - p0] = silu_f(u);
  }
  __syncthreads();
  for (int it = 0; it < 8; ++it) {
    int pp = it*8 + (t >> 5);
    int cc = t & 31;
    h0h[((size_t)(b*4096 + p0 + pp))*256 + c0 + cc] = f2h(tile[cc][pp]);
  }
}

// ---------- offset conv MFMA (fp16): 32 px x 32 oc (27 used) ----------
__global__ __launch_bounds__(256) void offset_mfma_kernel(
    const unsigned short* __restrict__ h0h, const unsigned short* __restrict__ wt,
    const float* __restrict__ off_b, float* __restrict__ off_t)
{
  int bid = blockIdx.x;
  int b  = bid & 7;                            // XCD swizzle
  int p0 = (bid >> 3) * 32;
  int y = p0 >> 6, xb = p0 & 63;
  int t = threadIdx.x;
  int lane = t & 63, wv = t >> 6;
  int r = lane & 15, g = lane >> 4;

  __shared__ unsigned short aw[3*34*SSTR];

  const unsigned short* hbase = h0h + (size_t)b*1048576;
  for (int idx = t; idx < 3264; idx += 256) {
    int row = idx / 1088, rem = idx - row*1088;
    int px = rem >> 5, c8 = rem & 31;
    int yy = y + row - 1, xx = xb - 1 + px;
    s16x8 v = {0,0,0,0,0,0,0,0};
    if (yy >= 0 && yy < 64 && xx >= 0 && xx < 64)
      v = *(const s16x8*)&hbase[((size_t)yy*64 + xx)*256 + c8*8];
    *(s16x8*)&aw[(row*34 + px)*SSTR + c8*8] = v;
  }
  __syncthreads();

  int m = wv & 1, n = wv >> 1;                 // wave -> (px half, oc half)
  f32x4 acc = {0.f,0.f,0.f,0.f};
  for (int k = 0; k < 9; ++k) {
    int ky = k/3, kxo = k%3;
    const unsigned short* abase = &aw[(ky*34)*SSTR];
    const unsigned short* wk = wt + (size_t)k*8192;   // [32 c8][32 o][8]
    #pragma unroll
    for (int kc = 0; kc < 8; ++kc) {
      h16x8 a  = *(const h16x8*)&abase[(kxo + m*16 + r)*SSTR + kc*32 + g*8];
      h16x8 bf = *(const h16x8*)&wk[(size_t)((kc*4 + g)*32 + n*16 + r)*8];
      acc = __builtin_amdgcn_mfma_f32_16x16x32_f16(a, bf, acc, 0, 0, 0);
    }
  }

  int oc = n*16 + r;
  if (oc < 27) {
    float bs = off_b[oc];
    #pragma unroll
    for (int j = 0; j < 4; ++j) {
      int px = m*16 + g*4 + j;
      off_t[((size_t)(b*4096) + p0 + px)*27 + oc] = acc[j] + bs;
    }
  }
}

// ---------- deformable conv (fp16): M=32, 4 blocks/CU, pre[8] resident ----------
__global__ __launch_bounds__(512, 2) void deform_mfma_kernel(
    const unsigned short* __restrict__ h0h, const float* __restrict__ off_t,
    const unsigned short* __restrict__ wt, const float* __restrict__ dcn_b,
    const float* __restrict__ tproj, unsigned short* __restrict__ h1h)
{
  int bid = blockIdx.x;                        // 1024 blocks
  int b  = bid & 7;                            // XCD swizzle (1024 % 8 == 0)
  int p0 = (bid >> 3) * 32;                    // 32 px, same row
  int t = threadIdx.x;                         // 0..511
  int lane = t & 63, wv = t >> 6;              // 8 waves
  int r = lane & 15, g = lane >> 4;

  __shared__ unsigned short samp[2][32*SSTR];  // dbuf 34.8KB
  __shared__ int    pki[288];
  __shared__ float4 pkw[288];                  // total 40.6KB -> 4 blk/CU

  for (int tp = t; tp < 288; tp += 512) {      // 32 px x 9 taps
    int i = tp / 9, k = tp - i*9;
    int p = p0 + i; int y = p >> 6, xq = p & 63;
    const float* ob = off_t + ((size_t)(b*4096) + p)*27;
    float dy = ob[2*k], dx = ob[2*k+1];
    float mask = 1.f / (1.f + __expf(-ob[18+k]));
    float py = dy + (float)(k/3 + y - 1);
    float px = dx + (float)(k%3 + xq - 1);
    float fy0 = floorf(py), fx0 = floorf(px);
    float wy1 = py - fy0, wx1 = px - fx0;
    int y0 = (int)fy0, x0 = (int)fx0, y1 = y0+1, x1 = x0+1;
    float vy0 = (y0 >= 0 && y0 < 64) ? 1.f : 0.f;
    float vy1 = (y1 >= 0 && y1 < 64) ? 1.f : 0.f;
    float vx0 = (x0 >= 0 && x0 < 64) ? 1.f : 0.f;
    float vx1 = (x1 >= 0 && x1 < 64) ? 1.f : 0.f;
    int iy0 = min(max(y0,0),63), ix0 = min(max(x0,0),63);
    int iy1 = min(max(y1,0),63), ix1 = min(max(x1,0),63);
    pki[tp] = iy0 | (ix0 << 8) | (iy1 << 16) | (ix1 << 24);
    float4 w;
    w.x = (1.f-wy1)*(1.f-wx1)*vy0*vx0*mask;
    w.y = (1.f-wy1)*wx1      *vy0*vx1*mask;
    w.z = wy1      *(1.f-wx1)*vy1*vx0*mask;
    w.w = wy1      *wx1      *vy1*vx1*mask;
    pkw[tp] = w;
  }
  __syncthreads();

  f32x4 zero4 = {0.f,0.f,0.f,0.f};
  f32x4 acc[2][2];
  #pragma unroll
  for (int m = 0; m < 2; ++m) { acc[m][0] = zero4; acc[m][1] = zero4; }

  const unsigned short* hb = h0h + (size_t)b*1048576;
  int px = t >> 4;                             // 16 threads per pixel (32 px)
  int ci = (t & 15) * 16;                      // 16 contiguous channels each
  int o_base = wv*32 + r;                      // 8 waves x UNIQUE 32-out slice

  h16x8 pre[8];                                // 4 corners x 16ch = 32 VGPR
  auto loadk = [&](int kk) {
    int tp = px*9 + kk;
    int pk = pki[tp];
    int iy0 = pk & 255, ix0 = (pk >> 8) & 255, iy1 = (pk >> 16) & 255, ix1 = (pk >> 24) & 255;
    const h16x8* q00 = (const h16x8*)(hb + ((size_t)iy0*64 + ix0)*256 + ci);
    const h16x8* q01 = (const h16x8*)(hb + ((size_t)iy0*64 + ix1)*256 + ci);
    const h16x8* q10 = (const h16x8*)(hb + ((size_t)iy1*64 + ix0)*256 + ci);
    const h16x8* q11 = (const h16x8*)(hb + ((size_t)iy1*64 + ix1)*256 + ci);
    pre[0] = q00[0]; pre[1] = q00[1];
    pre[2] = q01[0]; pre[3] = q01[1];
    pre[4] = q10[0]; pre[5] = q10[1];
    pre[6] = q11[0]; pre[7] = q11[1];
  };

  loadk(0);
  for (int k = 0; k < 9; ++k) {
    { // pk-fma weighted sum from prefetch regs -> LDS buf k&1
      int tp = px*9 + k;
      float4 w = pkw[tp];
      _Float16 w00 = (_Float16)w.x, w01 = (_Float16)w.y;
      _Float16 w10 = (_Float16)w.z, w11 = (_Float16)w.w;
      unsigned short* sp = &samp[k & 1][px*SSTR + ci];
      #pragma unroll
      for (int ch = 0; ch < 2; ++ch) {
        h16x8 o = pre[ch]*w00 + pre[2+ch]*w01 + pre[4+ch]*w10 + pre[6+ch]*w11;
        *(h16x8*)(sp + ch*8) = o;
      }
    }
    if (k < 8) loadk(k+1);                     // pre[8] stays resident
    asm volatile("s_waitcnt lgkmcnt(0)" ::: "memory");
    __builtin_amdgcn_s_barrier();

    const unsigned short* sb = samp[k & 1];
    const unsigned short* wk = wt + (size_t)k*65536;   // [32][256][8] this tap
    #pragma unroll
    for (int kc = 0; kc < 8; ++kc) {
      h16x8 a0 = *(const h16x8*)&sb[(     r)*SSTR + kc*32 + g*8];
      h16x8 a1 = *(const h16x8*)&sb[(16 + r)*SSTR + kc*32 + g*8];
      const unsigned short* wb = wk + (size_t)(kc*4 + g)*2048 + o_base*8;
      h16x8 b0 = *(const h16x8*)&wb[  0*8];
      h16x8 b1 = *(const h16x8*)&wb[ 16*8];
      acc[0][0] = __builtin_amdgcn_mfma_f32_16x16x32_f16(a0, b0, acc[0][0], 0, 0, 0);
      acc[0][1] = __builtin_amdgcn_mfma_f32_16x16x32_f16(a0, b1, acc[0][1], 0, 0, 0);
      acc[1][0] = __builtin_amdgcn_mfma_f32_16x16x32_f16(a1, b0, acc[1][0], 0, 0, 0);
      acc[1][1] = __builtin_amdgcn_mfma_f32_16x16x32_f16(a1, b1, acc[1][1], 0, 0, 0);
    }
    // no second barrier: next tap writes the other buffer (WAR safe)
  }

  #pragma unroll
  for (int nn = 0; nn < 2; ++nn) {
    int o = o_base + nn*16;
    float bs = dcn_b[o] + tproj[b*256 + o];
    #pragma unroll
    for (int m = 0; m < 2; ++m)
      #pragma unroll
      for (int j = 0; j < 4; ++j) {
        int pxl = m*16 + g*4 + j;
        h1h[((size_t)(b*4096) + p0 + pxl)*256 + o] = f2h(acc[m][nn][j] + bs);
      }
  }
}

// ---------- conv1 (fp16) M=32, adagn/silu fused staging, 2 blocks/CU ----------
__global__ __launch_bounds__(512, 2) void conv1_mfma_kernel(
    const unsigned short* __restrict__ h1h, const float* __restrict__ style1,
    const float* __restrict__ mu, const float* __restrict__ rs,
    const unsigned short* __restrict__ wt,
    const float* __restrict__ c1_b, const float* __restrict__ x,
    float* __restrict__ out)
{
  int bid = blockIdx.x;                        // 1024 blocks
  int b  = bid & 7;                            // XCD swizzle
  int p0 = (bid >> 3) * 32;
  int y = p0 >> 6, xb = p0 & 63;
  int t = threadIdx.x;                         // 0..511
  int lane = t & 63, wv = t >> 6;              // 8 waves
  int r = lane & 15, g = lane >> 4;

  __shared__ unsigned short aw[3*34*SSTR];     // 55.5KB -> 2 blk/CU

  const unsigned short* h1base = h1h + (size_t)b*1048576;
  for (int idx = t; idx < 3264; idx += 512) {  // 3 rows * 34 px * 32 chunks(8c)
    int row = idx / 1088, rem = idx - row*1088;
    int px = rem >> 5, c8 = rem & 31;
    int yy = y + row - 1, xx = xb - 1 + px;
    s16x8 v = {0,0,0,0,0,0,0,0};
    if (yy >= 0 && yy < 64 && xx >= 0 && xx < 64) {
      s16x8 h = *(const s16x8*)&h1base[((size_t)yy*64 + xx)*256 + c8*8];
      float m  = mu[b*32+c8], rr = rs[b*32+c8];
      #pragma unroll
      for (int j = 0; j < 8; ++j) {
        int c = c8*8 + j;
        float ga = style1[b*512 + c], be = style1[b*512 + 256 + c];
        float u = ga * (h2f((unsigned short)h[j]) - m) * rr + be;
        v[j] = (short)f2h(silu_f(u));
      }
    }
    *(s16x8*)&aw[(row*34 + px)*SSTR + c8*8] = v;
  }
  __syncthreads();

  f32x4 zero4 = {0.f,0.f,0.f,0.f};
  f32x4 acc[2][2];
  #pragma unroll
  for (int m = 0; m < 2; ++m) { acc[m][0] = zero4; acc[m][1] = zero4; }

  int o_base = wv*32 + r;                      // 8 waves x UNIQUE 32-out slice
  for (int k = 0; k < 9; ++k) {
    int ky = k/3, kxo = k%3;
    const unsigned short* abase = &aw[(ky*34)*SSTR];
    const unsigned short* wk = wt + (size_t)k*65536;
    #pragma unroll
    for (int kc = 0; kc < 8; ++kc) {
      h16x8 a0 = *(const h16x8*)&abase[(kxo +      r)*SSTR + kc*32 + g*8];
      h16x8 a1 = *(const h16x8*)&abase[(kxo + 16 + r)*SSTR + kc*32 + g*8];
      const unsigned short* wb = wk + (size_t)(kc*4 + g)*2048 + o_base*8;
      h16x8 b0 = *(const h16x8*)&wb[  0*8];
      h16x8 b1 = *(const h16x8*)&wb[ 16*8];
      acc[0][0] = __builtin_amdgcn_mfma_f32_16x16x32_f16(a0, b0, acc[0][0], 0, 0, 0);
      acc[0][1] = __builtin_amdgcn_mfma_f32_16x16x32_f16(a0, b1, acc[0][1], 0, 0, 0);
      acc[1][0] = __builtin_amdgcn_mfma_f32_16x16x32_f16(a1, b0, acc[1][0], 0, 0, 0);
      acc[1][1] = __builtin_amdgcn_mfma_f32_16x16x32_f16(a1, b1, acc[1][1], 0, 0, 0);
    }
  }

  #pragma unroll
  for (int nn = 0; nn < 2; ++nn) {
    int o = o_base + nn*16;
    float cb = c1_b[o];
    #pragma unroll
    for (int m = 0; m < 2; ++m)
      #pragma unroll
      for (int j = 0; j < 4; ++j) {
        int pxl = m*16 + g*4 + j;
        size_t oi = ((size_t)(b*256 + o))*4096 + p0 + pxl;
        out[oi] = x[oi] + acc[m][nn][j] + cb;
      }
  }
}

extern "C" void kernel_launch(void* const* d_in, const int* in_sizes, int n_in,
                              void* d_out, int out_size, void* d_ws, size_t ws_size,
                              hipStream_t stream) {
  const float* x    = (const float*)d_in[0];
  const float* temb = (const float*)d_in[1];
  const float* zemb = (const float*)d_in[2];
  const float* g0w  = (const float*)d_in[3];
  const float* g0b  = (const float*)d_in[4];
  const float* offw = (const float*)d_in[5];
  const float* offb = (const float*)d_in[6];
  const float* dcnw = (const float*)d_in[7];
  const float* dcnb = (const float*)d_in[8];
  const float* d0w  = (const float*)d_in[9];
  const float* d0b  = (const float*)d_in[10];
  const float* g1w  = (const float*)d_in[11];
  const float* g1b  = (const float*)d_in[12];
  const float* c1w  = (const float*)d_in[13];
  const float* c1b  = (const float*)d_in[14];
  float* out = (float*)d_out;
  float* ws  = (float*)d_ws;

  unsigned short* h0h = (unsigned short*)(ws + WS_H0B);
  unsigned short* h1h = (unsigned short*)(ws + WS_H1B);
  float* off_t   = ws + WS_OFFT;
  unsigned short* wtd  = (unsigned short*)(ws + WS_WTD);
  unsigned short* wtc  = (unsigned short*)(ws + WS_WTC);
  unsigned short* owtb = (unsigned short*)(ws + WS_OFFWTB);
  float* style0  = ws + WS_STYLE0;
  float* style1  = ws + WS_STYLE1;
  float* tproj   = ws + WS_TPROJ;
  float* mu0     = ws + WS_MU0;
  float* rs0     = ws + WS_RS0;
  float* mu1     = ws + WS_MU1;
  float* rs1     = ws + WS_RS1;

  prep_kernel<<<4936, 256, 0, stream>>>(zemb, temb, g0w, g0b, g1w, g1b, d0w, d0b,
                                        dcnw, c1w, offw, wtd, wtc, owtb,
                                        style0, style1, tproj);
  gn0_stats_kernel<<<256, 256, 0, stream>>>(x, mu0, rs0);
  h0_kernel<<<4096, 256, 0, stream>>>(x, style0, mu0, rs0, h0h);
  offset_mfma_kernel<<<1024, 256, 0, stream>>>(h0h, owtb, offb, off_t);
  deform_mfma_kernel<<<1024, 512, 0, stream>>>(h0h, off_t, wtd, dcnb, tproj, h1h);
  gn1_stats_kernel<<<256, 256, 0, stream>>>(h1h, mu1, rs1);
  conv1_mfma_kernel<<<1024, 512, 0, stream>>>(h1h, style1, mu1, rs1, wtc, c1b, x, out);
}

// Round 26
// 230.721 us; speedup vs baseline: 1.0578x; 1.0246x over previous
//
#include <hip/hip_runtime.h>
#include <hip/hip_bf16.h>

// ResnetBlockDDPMpp_Adagn: B=8, CIN=COUT=256, H=W=64, G=32, K=3
// Round 26 (on R25 pass, 236.4us == R22's 236.2, config verified twice):
//  - deform/conv1 exhausted (every structural lever measured over 20 rounds;
//    both ~2x over the 19us MFMA floor on the serialized-gather structure).
//  - Tail attack: merge gn0_stats INTO prep as 256 extra blocks (independent
//    inputs/outputs) -> gn0's ~10us HBM read overlaps prep's weight packs,
//    one fewer launch. Everything else byte-identical to R25.

#define EPSV 1e-6f

typedef short    s16x8 __attribute__((ext_vector_type(8)));   // raw 8x16b storage
typedef _Float16 h16x8 __attribute__((ext_vector_type(8)));   // fp16 math/MFMA
typedef float    f32x4 __attribute__((ext_vector_type(4)));

__device__ __forceinline__ float silu_f(float v){ return v / (1.f + __expf(-v)); }
__device__ __forceinline__ unsigned short f2h(float f){
  _Float16 h = (_Float16)f; unsigned short u; __builtin_memcpy(&u, &h, 2); return u;
}
__device__ __forceinline__ float h2f(unsigned short u){
  _Float16 h; __builtin_memcpy(&h, &u, 2); return (float)h;
}

// ---------------- ws layout (float units) ----------------
#define WS_H0B     0            // 8*4096*256 fp16
#define WS_H1B     4194304      // 8*4096*256 fp16
#define WS_OFFT    8388608      // 8*4096*27 fp32
#define WS_WTD     9273344      // dcn fp16 [9][32][256][8]
#define WS_WTC     9568256      // conv1 fp16 same
#define WS_OFFWTB  9863168      // offw fp16 [9][32][32][8]
#define WS_STYLE0  9900032
#define WS_STYLE1  9904128
#define WS_TPROJ   9908224
#define WS_MU0     9910272
#define WS_RS0     9910528
#define WS_MU1     9910784
#define WS_RS1     9911040
// end 9,911,296 floats = 39.6 MB

#define SSTR 272   // LDS row stride (ushorts): 544B, 16B-aligned

// ---------- reductions ----------
__device__ __forceinline__ void block_reduce2(float& s, float& q){
  for (int off = 32; off > 0; off >>= 1) {
    s += __shfl_down(s, off, 64);
    q += __shfl_down(q, off, 64);
  }
  __shared__ float ss[4], qs[4];
  int wid = threadIdx.x >> 6, lane = threadIdx.x & 63;
  if (lane == 0) { ss[wid] = s; qs[wid] = q; }
  __syncthreads();
  if (threadIdx.x == 0) { s = ss[0]+ss[1]+ss[2]+ss[3]; q = qs[0]+qs[1]+qs[2]+qs[3]; }
}

// ---------- prep: weight packs + tiny GEMMs + gn0 stats (merged) ----------
__global__ __launch_bounds__(256) void prep_kernel(
    const float* __restrict__ zemb, const float* __restrict__ temb,
    const float* __restrict__ g0w, const float* __restrict__ g0b,
    const float* __restrict__ g1w, const float* __restrict__ g1b,
    const float* __restrict__ d0w, const float* __restrict__ d0b,
    const float* __restrict__ dcn_w, const float* __restrict__ c1w,
    const float* __restrict__ offw, const float* __restrict__ x,
    unsigned short* __restrict__ wtd, unsigned short* __restrict__ wtc,
    unsigned short* __restrict__ offwtb,
    float* __restrict__ style0, float* __restrict__ style1, float* __restrict__ tproj,
    float* __restrict__ mu0, float* __restrict__ rs0)
{
  int blk = blockIdx.x, t = threadIdx.x;
  if (blk < 2304) {                       // dcn pack: e=((k*32+c8)*256+o)*8+j
    int e = blk*256 + t;
    int j = e & 7, o = (e >> 3) & 255, c8 = (e >> 11) & 31, k = e >> 16;
    wtd[e] = f2h(dcn_w[((o*256 + c8*8 + j)*9) + k]);
  } else if (blk < 4608) {                // conv1 pack
    int e = (blk-2304)*256 + t;
    int j = e & 7, o = (e >> 3) & 255, c8 = (e >> 11) & 31, k = e >> 16;
    wtc[e] = f2h(c1w[((o*256 + c8*8 + j)*9) + k]);
  } else if (blk < 4896) {                // offw pack: [9][32 c8][32 o][8 j], oc>=27 -> 0
    int e = (blk-4608)*256 + t;           // 73728 elems
    int j = e & 7, o = (e >> 3) & 31, c8 = (e >> 8) & 31, k = e >> 13;
    int c = c8*8 + j;
    offwtb[e] = (o < 27) ? f2h(offw[((o*256 + c)*9) + k]) : (unsigned short)0;
  } else if (blk < 4912) {                // style0 = zemb @ g0w.T + g0b (8x512)
    int e = (blk-4896)*256 + t; int b = e >> 9, j = e & 511;
    float s = g0b[j];
    const float* z = zemb + b*256; const float* w = g0w + j*256;
    for (int i = 0; i < 256; ++i) s += z[i]*w[i];
    style0[e] = s;
  } else if (blk < 4928) {                // style1
    int e = (blk-4912)*256 + t; int b = e >> 9, j = e & 511;
    float s = g1b[j];
    const float* z = zemb + b*256; const float* w = g1w + j*256;
    for (int i = 0; i < 256; ++i) s += z[i]*w[i];
    style1[e] = s;
  } else if (blk < 4936) {                // tproj = silu(temb) @ d0w.T + d0b (8x256)
    int e = (blk-4928)*256 + t; int b = e >> 8, o = e & 255;
    float s = d0b[o];
    const float* tb = temb + b*512; const float* w = d0w + o*512;
    for (int i = 0; i < 512; ++i) s += silu_f(tb[i])*w[i];
    tproj[e] = s;
  } else {                                // gn0 stats: blk2 = b*32+g over x (NCHW)
    int blk2 = blk - 4936;                // 256 blocks
    const float4* p4 = (const float4*)(x + (size_t)blk2*32768);
    float s = 0.f, q = 0.f;
    for (int i = t; i < 8192; i += 256) {
      float4 v = p4[i];
      s += v.x+v.y+v.z+v.w;
      q += v.x*v.x + v.y*v.y + v.z*v.z + v.w*v.w;
    }
    block_reduce2(s, q);
    if (t == 0) {
      float m = s * (1.f/32768.f);
      float var = q * (1.f/32768.f) - m*m;
      mu0[blk2] = m; rs0[blk2] = rsqrtf(var + EPSV);
    }
  }
}

// GN stats over h1 (fp16 NHWC)
__global__ __launch_bounds__(256) void gn1_stats_kernel(
    const unsigned short* __restrict__ h1h, float* __restrict__ mu, float* __restrict__ rs)
{
  int blk = blockIdx.x;  // b*32+g
  int b = blk >> 5, g = blk & 31;
  const unsigned short* base = h1h + (size_t)b*1048576 + g*8;
  float s = 0.f, q = 0.f;
  for (int px = threadIdx.x; px < 4096; px += 256) {
    s16x8 v = *(const s16x8*)(base + (size_t)px*256);
    #pragma unroll
    for (int e = 0; e < 8; ++e) {
      float f = h2f((unsigned short)v[e]);
      s += f; q += f*f;
    }
  }
  block_reduce2(s, q);
  if (threadIdx.x == 0) {
    float m = s * (1.f/32768.f);
    float var = q * (1.f/32768.f) - m*m;
    mu[blk] = m; rs[blk] = rsqrtf(var + EPSV);
  }
}

// ---------- h0 = silu(adagn(x)) NCHW -> NHWC fp16 ----------
__global__ __launch_bounds__(256) void h0_kernel(
    const float* __restrict__ x, const float* __restrict__ style0,
    const float* __restrict__ mu, const float* __restrict__ rs,
    unsigned short* __restrict__ h0h)
{
  int blk = blockIdx.x;          // b(8) x ptile(64) x ctile(8)
  int b  = blk >> 9;
  int pt = (blk >> 3) & 63;
  int ct = blk & 7;
  __shared__ float tile[32][65];
  int p0 = pt*64, c0 = ct*32;
  int t = threadIdx.x;
  for (int it = 0; it < 8; ++it) {
    int c = c0 + it*4 + (t >> 6);
    int p = p0 + (t & 63);
    float v = x[((size_t)(b*256 + c))*4096 + p];
    int g = c >> 3;
    float m  = mu[b*32+g], r = rs[b*32+g];
    float ga = style0[b*512 + c], be = style0[b*512 + 256 + c];
    float u = ga * (v - m) * r + be;
    tile[c - c0][p - p0] = silu_f(u);
  }
  __syncthreads();
  for (int it = 0; it < 8; ++it) {
    int pp = it*8 + (t >> 5);
    int cc = t & 31;
    h0h[((size_t)(b*4096 + p0 + pp))*256 + c0 + cc] = f2h(tile[cc][pp]);
  }
}

// ---------- offset conv MFMA (fp16): 32 px x 32 oc (27 used) ----------
__global__ __launch_bounds__(256) void offset_mfma_kernel(
    const unsigned short* __restrict__ h0h, const unsigned short* __restrict__ wt,
    const float* __restrict__ off_b, float* __restrict__ off_t)
{
  int bid = blockIdx.x;
  int b  = bid & 7;                            // XCD swizzle
  int p0 = (bid >> 3) * 32;
  int y = p0 >> 6, xb = p0 & 63;
  int t = threadIdx.x;
  int lane = t & 63, wv = t >> 6;
  int r = lane & 15, g = lane >> 4;

  __shared__ unsigned short aw[3*34*SSTR];

  const unsigned short* hbase = h0h + (size_t)b*1048576;
  for (int idx = t; idx < 3264; idx += 256) {
    int row = idx / 1088, rem = idx - row*1088;
    int px = rem >> 5, c8 = rem & 31;
    int yy = y + row - 1, xx = xb - 1 + px;
    s16x8 v = {0,0,0,0,0,0,0,0};
    if (yy >= 0 && yy < 64 && xx >= 0 && xx < 64)
      v = *(const s16x8*)&hbase[((size_t)yy*64 + xx)*256 + c8*8];
    *(s16x8*)&aw[(row*34 + px)*SSTR + c8*8] = v;
  }
  __syncthreads();

  int m = wv & 1, n = wv >> 1;                 // wave -> (px half, oc half)
  f32x4 acc = {0.f,0.f,0.f,0.f};
  for (int k = 0; k < 9; ++k) {
    int ky = k/3, kxo = k%3;
    const unsigned short* abase = &aw[(ky*34)*SSTR];
    const unsigned short* wk = wt + (size_t)k*8192;   // [32 c8][32 o][8]
    #pragma unroll
    for (int kc = 0; kc < 8; ++kc) {
      h16x8 a  = *(const h16x8*)&abase[(kxo + m*16 + r)*SSTR + kc*32 + g*8];
      h16x8 bf = *(const h16x8*)&wk[(size_t)((kc*4 + g)*32 + n*16 + r)*8];
      acc = __builtin_amdgcn_mfma_f32_16x16x32_f16(a, bf, acc, 0, 0, 0);
    }
  }

  int oc = n*16 + r;
  if (oc < 27) {
    float bs = off_b[oc];
    #pragma unroll
    for (int j = 0; j < 4; ++j) {
      int px = m*16 + g*4 + j;
      off_t[((size_t)(b*4096) + p0 + px)*27 + oc] = acc[j] + bs;
    }
  }
}

// ---------- deformable conv (fp16): M=32, 4 blocks/CU, pre[8] resident ----------
__global__ __launch_bounds__(512, 2) void deform_mfma_kernel(
    const unsigned short* __restrict__ h0h, const float* __restrict__ off_t,
    const unsigned short* __restrict__ wt, const float* __restrict__ dcn_b,
    const float* __restrict__ tproj, unsigned short* __restrict__ h1h)
{
  int bid = blockIdx.x;                        // 1024 blocks
  int b  = bid & 7;                            // XCD swizzle (1024 % 8 == 0)
  int p0 = (bid >> 3) * 32;                    // 32 px, same row
  int t = threadIdx.x;                         // 0..511
  int lane = t & 63, wv = t >> 6;              // 8 waves
  int r = lane & 15, g = lane >> 4;

  __shared__ unsigned short samp[2][32*SSTR];  // dbuf 34.8KB
  __shared__ int    pki[288];
  __shared__ float4 pkw[288];                  // total 40.6KB -> 4 blk/CU

  for (int tp = t; tp < 288; tp += 512) {      // 32 px x 9 taps
    int i = tp / 9, k = tp - i*9;
    int p = p0 + i; int y = p >> 6, xq = p & 63;
    const float* ob = off_t + ((size_t)(b*4096) + p)*27;
    float dy = ob[2*k], dx = ob[2*k+1];
    float mask = 1.f / (1.f + __expf(-ob[18+k]));
    float py = dy + (float)(k/3 + y - 1);
    float px = dx + (float)(k%3 + xq - 1);
    float fy0 = floorf(py), fx0 = floorf(px);
    float wy1 = py - fy0, wx1 = px - fx0;
    int y0 = (int)fy0, x0 = (int)fx0, y1 = y0+1, x1 = x0+1;
    float vy0 = (y0 >= 0 && y0 < 64) ? 1.f : 0.f;
    float vy1 = (y1 >= 0 && y1 < 64) ? 1.f : 0.f;
    float vx0 = (x0 >= 0 && x0 < 64) ? 1.f : 0.f;
    float vx1 = (x1 >= 0 && x1 < 64) ? 1.f : 0.f;
    int iy0 = min(max(y0,0),63), ix0 = min(max(x0,0),63);
    int iy1 = min(max(y1,0),63), ix1 = min(max(x1,0),63);
    pki[tp] = iy0 | (ix0 << 8) | (iy1 << 16) | (ix1 << 24);
    float4 w;
    w.x = (1.f-wy1)*(1.f-wx1)*vy0*vx0*mask;
    w.y = (1.f-wy1)*wx1      *vy0*vx1*mask;
    w.z = wy1      *(1.f-wx1)*vy1*vx0*mask;
    w.w = wy1      *wx1      *vy1*vx1*mask;
    pkw[tp] = w;
  }
  __syncthreads();

  f32x4 zero4 = {0.f,0.f,0.f,0.f};
  f32x4 acc[2][2];
  #pragma unroll
  for (int m = 0; m < 2; ++m) { acc[m][0] = zero4; acc[m][1] = zero4; }

  const unsigned short* hb = h0h + (size_t)b*1048576;
  int px = t >> 4;                             // 16 threads per pixel (32 px)
  int ci = (t & 15) * 16;                      // 16 contiguous channels each
  int o_base = wv*32 + r;                      // 8 waves x UNIQUE 32-out slice

  h16x8 pre[8];                                // 4 corners x 16ch = 32 VGPR
  auto loadk = [&](int kk) {
    int tp = px*9 + kk;
    int pk = pki[tp];
    int iy0 = pk & 255, ix0 = (pk >> 8) & 255, iy1 = (pk >> 16) & 255, ix1 = (pk >> 24) & 255;
    const h16x8* q00 = (const h16x8*)(hb + ((size_t)iy0*64 + ix0)*256 + ci);
    const h16x8* q01 = (const h16x8*)(hb + ((size_t)iy0*64 + ix1)*256 + ci);
    const h16x8* q10 = (const h16x8*)(hb + ((size_t)iy1*64 + ix0)*256 + ci);
    const h16x8* q11 = (const h16x8*)(hb + ((size_t)iy1*64 + ix1)*256 + ci);
    pre[0] = q00[0]; pre[1] = q00[1];
    pre[2] = q01[0]; pre[3] = q01[1];
    pre[4] = q10[0]; pre[5] = q10[1];
    pre[6] = q11[0]; pre[7] = q11[1];
  };

  loadk(0);
  for (int k = 0; k < 9; ++k) {
    { // pk-fma weighted sum from prefetch regs -> LDS buf k&1
      int tp = px*9 + k;
      float4 w = pkw[tp];
      _Float16 w00 = (_Float16)w.x, w01 = (_Float16)w.y;
      _Float16 w10 = (_Float16)w.z, w11 = (_Float16)w.w;
      unsigned short* sp = &samp[k & 1][px*SSTR + ci];
      #pragma unroll
      for (int ch = 0; ch < 2; ++ch) {
        h16x8 o = pre[ch]*w00 + pre[2+ch]*w01 + pre[4+ch]*w10 + pre[6+ch]*w11;
        *(h16x8*)(sp + ch*8) = o;
      }
    }
    if (k < 8) loadk(k+1);                     // pre[8] stays resident
    asm volatile("s_waitcnt lgkmcnt(0)" ::: "memory");
    __builtin_amdgcn_s_barrier();

    const unsigned short* sb = samp[k & 1];
    const unsigned short* wk = wt + (size_t)k*65536;   // [32][256][8] this tap
    #pragma unroll
    for (int kc = 0; kc < 8; ++kc) {
      h16x8 a0 = *(const h16x8*)&sb[(     r)*SSTR + kc*32 + g*8];
      h16x8 a1 = *(const h16x8*)&sb[(16 + r)*SSTR + kc*32 + g*8];
      const unsigned short* wb = wk + (size_t)(kc*4 + g)*2048 + o_base*8;
      h16x8 b0 = *(const h16x8*)&wb[  0*8];
      h16x8 b1 = *(const h16x8*)&wb[ 16*8];
      acc[0][0] = __builtin_amdgcn_mfma_f32_16x16x32_f16(a0, b0, acc[0][0], 0, 0, 0);
      acc[0][1] = __builtin_amdgcn_mfma_f32_16x16x32_f16(a0, b1, acc[0][1], 0, 0, 0);
      acc[1][0] = __builtin_amdgcn_mfma_f32_16x16x32_f16(a1, b0, acc[1][0], 0, 0, 0);
      acc[1][1] = __builtin_amdgcn_mfma_f32_16x16x32_f16(a1, b1, acc[1][1], 0, 0, 0);
    }
    // no second barrier: next tap writes the other buffer (WAR safe)
  }

  #pragma unroll
  for (int nn = 0; nn < 2; ++nn) {
    int o = o_base + nn*16;
    float bs = dcn_b[o] + tproj[b*256 + o];
    #pragma unroll
    for (int m = 0; m < 2; ++m)
      #pragma unroll
      for (int j = 0; j < 4; ++j) {
        int pxl = m*16 + g*4 + j;
        h1h[((size_t)(b*4096) + p0 + pxl)*256 + o] = f2h(acc[m][nn][j] + bs);
      }
  }
}

// ---------- conv1 (fp16) M=32, adagn/silu fused staging, 2 blocks/CU ----------
__global__ __launch_bounds__(512, 2) void conv1_mfma_kernel(
    const unsigned short* __restrict__ h1h, const float* __restrict__ style1,
    const float* __restrict__ mu, const float* __restrict__ rs,
    const unsigned short* __restrict__ wt,
    const float* __restrict__ c1_b, const float* __restrict__ x,
    float* __restrict__ out)
{
  int bid = blockIdx.x;                        // 1024 blocks
  int b  = bid & 7;                            // XCD swizzle
  int p0 = (bid >> 3) * 32;
  int y = p0 >> 6, xb = p0 & 63;
  int t = threadIdx.x;                         // 0..511
  int lane = t & 63, wv = t >> 6;              // 8 waves
  int r = lane & 15, g = lane >> 4;

  __shared__ unsigned short aw[3*34*SSTR];     // 55.5KB -> 2 blk/CU

  const unsigned short* h1base = h1h + (size_t)b*1048576;
  for (int idx = t; idx < 3264; idx += 512) {  // 3 rows * 34 px * 32 chunks(8c)
    int row = idx / 1088, rem = idx - row*1088;
    int px = rem >> 5, c8 = rem & 31;
    int yy = y + row - 1, xx = xb - 1 + px;
    s16x8 v = {0,0,0,0,0,0,0,0};
    if (yy >= 0 && yy < 64 && xx >= 0 && xx < 64) {
      s16x8 h = *(const s16x8*)&h1base[((size_t)yy*64 + xx)*256 + c8*8];
      float m  = mu[b*32+c8], rr = rs[b*32+c8];
      #pragma unroll
      for (int j = 0; j < 8; ++j) {
        int c = c8*8 + j;
        float ga = style1[b*512 + c], be = style1[b*512 + 256 + c];
        float u = ga * (h2f((unsigned short)h[j]) - m) * rr + be;
        v[j] = (short)f2h(silu_f(u));
      }
    }
    *(s16x8*)&aw[(row*34 + px)*SSTR + c8*8] = v;
  }
  __syncthreads();

  f32x4 zero4 = {0.f,0.f,0.f,0.f};
  f32x4 acc[2][2];
  #pragma unroll
  for (int m = 0; m < 2; ++m) { acc[m][0] = zero4; acc[m][1] = zero4; }

  int o_base = wv*32 + r;                      // 8 waves x UNIQUE 32-out slice
  for (int k = 0; k < 9; ++k) {
    int ky = k/3, kxo = k%3;
    const unsigned short* abase = &aw[(ky*34)*SSTR];
    const unsigned short* wk = wt + (size_t)k*65536;
    #pragma unroll
    for (int kc = 0; kc < 8; ++kc) {
      h16x8 a0 = *(const h16x8*)&abase[(kxo +      r)*SSTR + kc*32 + g*8];
      h16x8 a1 = *(const h16x8*)&abase[(kxo + 16 + r)*SSTR + kc*32 + g*8];
      const unsigned short* wb = wk + (size_t)(kc*4 + g)*2048 + o_base*8;
      h16x8 b0 = *(const h16x8*)&wb[  0*8];
      h16x8 b1 = *(const h16x8*)&wb[ 16*8];
      acc[0][0] = __builtin_amdgcn_mfma_f32_16x16x32_f16(a0, b0, acc[0][0], 0, 0, 0);
      acc[0][1] = __builtin_amdgcn_mfma_f32_16x16x32_f16(a0, b1, acc[0][1], 0, 0, 0);
      acc[1][0] = __builtin_amdgcn_mfma_f32_16x16x32_f16(a1, b0, acc[1][0], 0, 0, 0);
      acc[1][1] = __builtin_amdgcn_mfma_f32_16x16x32_f16(a1, b1, acc[1][1], 0, 0, 0);
    }
  }

  #pragma unroll
  for (int nn = 0; nn < 2; ++nn) {
    int o = o_base + nn*16;
    float cb = c1_b[o];
    #pragma unroll
    for (int m = 0; m < 2; ++m)
      #pragma unroll
      for (int j = 0; j < 4; ++j) {
        int pxl = m*16 + g*4 + j;
        size_t oi = ((size_t)(b*256 + o))*4096 + p0 + pxl;
        out[oi] = x[oi] + acc[m][nn][j] + cb;
      }
  }
}

extern "C" void kernel_launch(void* const* d_in, const int* in_sizes, int n_in,
                              void* d_out, int out_size, void* d_ws, size_t ws_size,
                              hipStream_t stream) {
  const float* x    = (const float*)d_in[0];
  const float* temb = (const float*)d_in[1];
  const float* zemb = (const float*)d_in[2];
  const float* g0w  = (const float*)d_in[3];
  const float* g0b  = (const float*)d_in[4];
  const float* offw = (const float*)d_in[5];
  const float* offb = (const float*)d_in[6];
  const float* dcnw = (const float*)d_in[7];
  const float* dcnb = (const float*)d_in[8];
  const float* d0w  = (const float*)d_in[9];
  const float* d0b  = (const float*)d_in[10];
  const float* g1w  = (const float*)d_in[11];
  const float* g1b  = (const float*)d_in[12];
  const float* c1w  = (const float*)d_in[13];
  const float* c1b  = (const float*)d_in[14];
  float* out = (float*)d_out;
  float* ws  = (float*)d_ws;

  unsigned short* h0h = (unsigned short*)(ws + WS_H0B);
  unsigned short* h1h = (unsigned short*)(ws + WS_H1B);
  float* off_t   = ws + WS_OFFT;
  unsigned short* wtd  = (unsigned short*)(ws + WS_WTD);
  unsigned short* wtc  = (unsigned short*)(ws + WS_WTC);
  unsigned short* owtb = (unsigned short*)(ws + WS_OFFWTB);
  float* style0  = ws + WS_STYLE0;
  float* style1  = ws + WS_STYLE1;
  float* tproj   = ws + WS_TPROJ;
  float* mu0     = ws + WS_MU0;
  float* rs0     = ws + WS_RS0;
  float* mu1     = ws + WS_MU1;
  float* rs1     = ws + WS_RS1;

  prep_kernel<<<5192, 256, 0, stream>>>(zemb, temb, g0w, g0b, g1w, g1b, d0w, d0b,
                                        dcnw, c1w, offw, x, wtd, wtc, owtb,
                                        style0, style1, tproj, mu0, rs0);
  h0_kernel<<<4096, 256, 0, stream>>>(x, style0, mu0, rs0, h0h);
  offset_mfma_kernel<<<1024, 256, 0, stream>>>(h0h, owtb, offb, off_t);
  deform_mfma_kernel<<<1024, 512, 0, stream>>>(h0h, off_t, wtd, dcnb, tproj, h1h);
  gn1_stats_kernel<<<256, 256, 0, stream>>>(h1h, mu1, rs1);
  conv1_mfma_kernel<<<1024, 512, 0, stream>>>(h1h, style1, mu1, rs1, wtc, c1b, x, out);
}